// Round 8
// baseline (6151.498 us; speedup 1.0000x reference)
//
#include <hip/hip_runtime.h>

#define THREADS 256
#define SPB 8   // samples per block, one per 32-lane half-wave

// fast reciprocal (v_rcp_f32, ~1 ulp); avoids the ~10-op IEEE divide sequence
__device__ __forceinline__ float frcp(float x){ return __builtin_amdgcn_rcpf(x); }
__device__ __forceinline__ float fsig(float x){ return frcp(1.0f + __expf(-x)); }
// tanh = 1 - 2/(e^{2x}+1): saturates at +-1, no clamp needed
__device__ __forceinline__ float ftanh(float x){
    float e = __expf(2.0f * x);
    return fmaf(-2.0f, frcp(e + 1.0f), 1.0f);
}
// NaN-PROPAGATING leaky relu
__device__ __forceinline__ float lrelu(float x){ return x > 0.0f ? x : 0.01f * x; }

__global__ void diag_kernel(float* outp, float code){ outp[0] = code; }

// 5-step LSTM recurrence, STREAMED W_hh: per k-chunk load 4x float4 from global
// (L1-hot, 4KB working set). Live weight state: 16 floats. Streamed loads are
// h-INDEPENDENT -> they issue under the serial activation tail; at 3 waves/SIMD
// the vmcnt waits are cross-covered by the other waves.
// h broadcast stays shfl (R2/R4: LDS round-trips in the recurrence regress).
__device__ __forceinline__ void lstm_rec_stream(const float* __restrict__ whh, int j,
                                                const float (&acc)[5][4],
                                                float* __restrict__ hline,
                                                float& s1o, float& s2o)
{
    const float* wr0 = whh + (size_t)(0*32 + j)*32;
    const float* wr1 = whh + (size_t)(1*32 + j)*32;
    const float* wr2 = whh + (size_t)(2*32 + j)*32;
    const float* wr3 = whh + (size_t)(3*32 + j)*32;
    float h = 0.0f, c = 0.0f, s1 = 0.0f, s2 = 0.0f;
    #pragma unroll
    for (int t = 0; t < 5; ++t){
        float q0 = acc[t][0], q1 = acc[t][1], q2 = acc[t][2], q3 = acc[t][3];
        if (t > 0){
            #pragma unroll
            for (int k0 = 0; k0 < 32; k0 += 4){
                float4 u0 = *(const float4*)(wr0 + k0);   // h-independent, L1-hot
                float4 u1 = *(const float4*)(wr1 + k0);
                float4 u2 = *(const float4*)(wr2 + k0);
                float4 u3 = *(const float4*)(wr3 + k0);
                float h0 = __shfl(h, k0+0, 32);           // half-wave broadcast
                float h1 = __shfl(h, k0+1, 32);
                float h2 = __shfl(h, k0+2, 32);
                float h3 = __shfl(h, k0+3, 32);
                q0 = fmaf(u0.x,h0, fmaf(u0.y,h1, fmaf(u0.z,h2, fmaf(u0.w,h3, q0))));
                q1 = fmaf(u1.x,h0, fmaf(u1.y,h1, fmaf(u1.z,h2, fmaf(u1.w,h3, q1))));
                q2 = fmaf(u2.x,h0, fmaf(u2.y,h1, fmaf(u2.z,h2, fmaf(u2.w,h3, q2))));
                q3 = fmaf(u3.x,h0, fmaf(u3.y,h1, fmaf(u3.z,h2, fmaf(u3.w,h3, q3))));
            }
        }
        float iv = fsig(q0), fv = fsig(q1), gv = ftanh(q2), ov = fsig(q3);
        c = fmaf(fv, c, iv * gv);
        h = ov * ftanh(c);
        s1 += h; s2 = fmaf(h, h, s2);
        hline[t*32 + j] = h;   // fire-and-forget; read only after recurrence ends
    }
    s1o = s1; s2o = s2;
}

// Occupancy model (R0-R7): waves/SIMD = floor(256/VGPR), blocks/CU = floor(160K/LDS).
// REVISED clamp rule (R7): without a min-waves bound the scheduler hoists loads to
// whatever VGPR count it likes (R7: 256!). A clamp is SAFE iff budget >= semantic
// minimum of live state: (256,3)=85 regs vs ~70 semantic min here -> feasible.
// (256,4)=64 was below R0's wh[4][32]=128 floor -> R1's spill disaster.
// Check on every run: WRITE_SIZE ~1.5KB means no spill; MBs means infeasible budget.
__global__ __launch_bounds__(THREADS, 3)
void reslstm_kernel(const float* __restrict__ data,
                    const float* __restrict__ wih0, const float* __restrict__ whh0,
                    const float* __restrict__ bih0, const float* __restrict__ bhh0,
                    const float* __restrict__ g0p,  const float* __restrict__ be0p,
                    const float* __restrict__ wih1, const float* __restrict__ whh1,
                    const float* __restrict__ bih1, const float* __restrict__ bhh1,
                    const float* __restrict__ g1p,  const float* __restrict__ be1p,
                    const float* __restrict__ dwp,  const float* __restrict__ dbp,
                    float* __restrict__ outp, int Btot)
{
    // LDS 53760 B <= 54613 -> 3 blocks/CU. dw/db NOT staged (direct L1-hot reads).
    __shared__ __attribute__((aligned(16))) float xs[SPB*320];     // 10.0 KB; x, later L1 h-scratch
    __shared__ __attribute__((aligned(16))) float wbuf[128*68];    // 34.8 KB; wih0 then wih1
    __shared__ __attribute__((aligned(16))) float out0s[SPB*160];  //  5.0 KB; layer-0 h, then out0
    __shared__ float bias0s[128], bias1s[128];
    __shared__ float g0s[160], be0s[160], g1s[160], be1s[160];

    const int tid = threadIdx.x;
    const int b0  = blockIdx.x * SPB;
    const int nsamp = (Btot - b0 < SPB) ? (Btot - b0) : SPB;

    // ---------------- stage (coalesced fp32 global -> LDS) ----------------
    {
        const float* dat = data + (size_t)b0 * 310;   // sample chunk: idx = n*5 + t
        for (int i = tid; i < nsamp*310; i += THREADS){
            int s = i / 310, r = i - s*310;
            int n = r / 5,   t = r - n*5;
            xs[s*320 + t*64 + n] = dat[i];
        }
        for (int i = tid; i < SPB*10; i += THREADS){          // zero pad n=62,63
            int s = i / 10, q = i - s*10;
            xs[s*320 + (q>>1)*64 + 62 + (q&1)] = 0.0f;
        }
        for (int i = tid; i < 128*62; i += THREADS){
            int row = i / 62, n = i - row*62;
            wbuf[row*68 + n] = wih0[i];
        }
        for (int i = tid; i < 128*6; i += THREADS){           // zero pad n=62..67
            int row = i / 6, n = i - row*6;
            wbuf[row*68 + 62 + n] = 0.0f;
        }
        if (tid < 128)  bias0s[tid] = bih0[tid] + bhh0[tid];
        else            { int q = tid - 128; bias1s[q] = bih1[q] + bhh1[q]; }
        if (tid < 160){
            g0s[tid] = g0p[tid];  be0s[tid] = be0p[tid];
            g1s[tid] = g1p[tid];  be1s[tid] = be1p[tid];
        }
    }
    __syncthreads();

    const int j = tid & 31;       // hidden unit owned by this lane
    const int s = tid >> 5;       // sample-in-block (half-wave)
    float* xsc = xs    + s*320;   // input; reused as layer-1 h scratch (same half-wave only)
    float* o0l = out0s + s*160;   // layer-0 h line, then out0 (post LN+lrelu)

    // ---------------- phase A: xg0 = x @ W_ih0^T + biases (float4 LDS reads) ----------------
    float acc[5][4];
    #pragma unroll
    for (int r = 0; r < 4; ++r){
        float bv = bias0s[r*32 + j];
        #pragma unroll
        for (int t = 0; t < 5; ++t) acc[t][r] = bv;
    }
    {
        const float* wp0 = wbuf + j*68;
        #pragma unroll 4
        for (int n0 = 0; n0 < 64; n0 += 4){
            float4 w[4];
            #pragma unroll
            for (int r = 0; r < 4; ++r)
                w[r] = *(const float4*)(wp0 + r*32*68 + n0);
            #pragma unroll
            for (int t = 0; t < 5; ++t){
                float4 xv = *(const float4*)(xsc + t*64 + n0);
                #pragma unroll
                for (int r = 0; r < 4; ++r)
                    acc[t][r] = fmaf(w[r].x, xv.x, fmaf(w[r].y, xv.y, fmaf(w[r].z, xv.z, fmaf(w[r].w, xv.w, acc[t][r]))));
            }
        }
    }

    // ---------------- layer 0 recurrence + LN + LeakyReLU ----------------
    {
        float s1, s2;
        lstm_rec_stream(whh0, j, acc, o0l, s1, s2);
        #pragma unroll
        for (int m = 1; m < 32; m <<= 1){
            s1 += __shfl_xor(s1, m, 64);   // masks <32 stay within the half-wave
            s2 += __shfl_xor(s2, m, 64);
        }
        float mu   = s1 * (1.0f/160.0f);
        float var  = s2 * (1.0f/160.0f) - mu*mu;
        float rstd = rsqrtf(var + 1e-5f);
        #pragma unroll
        for (int t = 0; t < 5; ++t){
            int ix = t*32 + j;
            float v = o0l[ix];
            o0l[ix] = lrelu(fmaf((v - mu)*rstd, g0s[ix], be0s[ix]));
        }
    }

    __syncthreads();
    // ---------------- restage wih1 into wbuf [128][36] ----------------
    for (int i = tid; i < 128*32; i += THREADS){
        int row = i >> 5, k = i & 31;
        wbuf[row*36 + k] = wih1[i];
    }
    for (int i = tid; i < 128*4; i += THREADS){
        int row = i >> 2;
        wbuf[row*36 + 32 + (i & 3)] = 0.0f;
    }
    __syncthreads();

    // ---------------- phase B: xg1 = out0 @ W_ih1^T + biases ----------------
    #pragma unroll
    for (int r = 0; r < 4; ++r){
        float bv = bias1s[r*32 + j];
        #pragma unroll
        for (int t = 0; t < 5; ++t) acc[t][r] = bv;
    }
    {
        const float* wp1 = wbuf + j*36;
        #pragma unroll 2
        for (int k0 = 0; k0 < 32; k0 += 4){
            float4 w[4];
            #pragma unroll
            for (int r = 0; r < 4; ++r)
                w[r] = *(const float4*)(wp1 + r*32*36 + k0);
            #pragma unroll
            for (int t = 0; t < 5; ++t){
                float4 ov = *(const float4*)(o0l + t*32 + k0);
                #pragma unroll
                for (int r = 0; r < 4; ++r)
                    acc[t][r] = fmaf(w[r].x, ov.x, fmaf(w[r].y, ov.y, fmaf(w[r].z, ov.z, fmaf(w[r].w, ov.w, acc[t][r]))));
            }
        }
    }

    // ---------------- layer 1 recurrence + LN + residual + head ----------------
    float p0 = 0.0f, p1 = 0.0f, p2 = 0.0f;
    {
        float s1, s2;
        lstm_rec_stream(whh1, j, acc, xsc, s1, s2);   // xs line reused as h scratch
        #pragma unroll
        for (int m = 1; m < 32; m <<= 1){
            s1 += __shfl_xor(s1, m, 64);
            s2 += __shfl_xor(s2, m, 64);
        }
        float mu   = s1 * (1.0f/160.0f);
        float var  = s2 * (1.0f/160.0f) - mu*mu;
        float rstd = rsqrtf(var + 1e-5f);
        #pragma unroll
        for (int t = 0; t < 5; ++t){
            int ix = t*32 + j;
            float v = xsc[ix];
            float y = lrelu(fmaf((v - mu)*rstd, g1s[ix], be1s[ix])) + o0l[ix];  // +residual
            // dense head, dw read direct from global (coalesced, L1-hot)
            p0 = fmaf(dwp[      ix], y, p0);
            p1 = fmaf(dwp[160 + ix], y, p1);
            p2 = fmaf(dwp[320 + ix], y, p2);
        }
    }
    #pragma unroll
    for (int m = 1; m < 32; m <<= 1){
        p0 += __shfl_xor(p0, m, 64);
        p1 += __shfl_xor(p1, m, 64);
        p2 += __shfl_xor(p2, m, 64);
    }
    if (j < 3 && s < nsamp){
        float v = (j == 0) ? p0 : ((j == 1) ? p1 : p2);
        v = lrelu(v + dbp[j]);
        outp[(size_t)(b0 + s)*3 + j] = v;
    }
}

extern "C" void kernel_launch(void* const* d_in, const int* in_sizes, int n_in,
                              void* d_out, int out_size, void* d_ws, size_t ws_size,
                              hipStream_t stream)
{
    (void)d_ws; (void)ws_size;

    const int B = out_size / 3;

    // Locate 'data' = largest input; infer the harness's input ordering from it.
    int idx_data = 0;
    for (int i = 1; i < n_in; ++i)
        if (in_sizes[i] > in_sizes[idx_data]) idx_data = i;

    // semantic slots (reference dict order):
    // 0 data,1 wih0,2 whh0,3 bih0,4 bhh0,5 g0,6 be0,7 wih1,8 whh1,9 bih1,
    // 10 bhh1,11 g1,12 be1,13 dw,14 db
    static const int dict_map[15]  = {0,1,2,3,4,5,6,7,8,9,10,11,12,13,14};
    // alphabetical key order fallback
    static const int alpha_map[15] = {6,13,11,2,0,9,4,14,12,3,1,10,5,8,7};
    static const int rev_map[15]   = {14,13,12,11,10,9,8,7,6,5,4,3,2,1,0};

    const int* map = dict_map;
    if (idx_data == 6)       map = alpha_map;
    else if (idx_data == 14) map = rev_map;

    long ds  = (long)in_sizes[idx_data];
    long ws0 = (long)in_sizes[map[1]];
    bool ok = (ds == (long)B*310 || ds == (long)B*620 || ds == (long)B*1240)
           && (ws0 == 7936 || ws0 == 15872 || ws0 == 31744);

    if (!ok || B <= 0){
        diag_kernel<<<1, 1, 0, stream>>>((float*)d_out, 100.0f + 10.0f*idx_data);
        return;
    }

    const float* P[15];
    for (int k = 0; k < 15; ++k) P[k] = (const float*)d_in[map[k]];

    const int nblocks = (B + SPB - 1) / SPB;
    reslstm_kernel<<<dim3(nblocks), dim3(THREADS), 0, stream>>>(
        P[0], P[1], P[2], P[3], P[4], P[5], P[6], P[7], P[8], P[9],
        P[10], P[11], P[12], P[13], P[14],
        (float*)d_out, B);
}

// Round 9
// 1202.072 us; speedup vs baseline: 5.1174x; 5.1174x over previous
//
#include <hip/hip_runtime.h>

#define THREADS 64   // ONE wave per block, 2 samples (one per 32-lane half-wave)
#define SPB 2

// fast reciprocal (v_rcp_f32, ~1 ulp); avoids the ~10-op IEEE divide sequence
__device__ __forceinline__ float frcp(float x){ return __builtin_amdgcn_rcpf(x); }
__device__ __forceinline__ float fsig(float x){ return frcp(1.0f + __expf(-x)); }
// tanh = 1 - 2/(e^{2x}+1): saturates at +-1, no clamp needed
__device__ __forceinline__ float ftanh(float x){
    float e = __expf(2.0f * x);
    return fmaf(-2.0f, frcp(e + 1.0f), 1.0f);
}
// NaN-PROPAGATING leaky relu
__device__ __forceinline__ float lrelu(float x){ return x > 0.0f ? x : 0.01f * x; }

__global__ void diag_kernel(float* outp, float code){ outp[0] = code; }

// load per-lane W_hh rows {j, 32+j, 64+j, 96+j} straight from global (L1-hot) as float4
__device__ __forceinline__ void load_wh_global(const float* __restrict__ whh, int j, float (&wh)[4][32]){
    #pragma unroll
    for (int r = 0; r < 4; ++r){
        const float* rp = whh + (r*32 + j)*32;
        #pragma unroll
        for (int q = 0; q < 8; ++q){
            float4 v = *(const float4*)(rp + q*4);
            wh[r][q*4+0] = v.x; wh[r][q*4+1] = v.y;
            wh[r][q*4+2] = v.z; wh[r][q*4+3] = v.w;
        }
    }
}

// 5-step LSTM recurrence (champion R6 structure, untouched): register wh, shfl h-broadcast
__device__ __forceinline__ void lstm_rec(const float (&wh)[4][32], const float (&acc)[5][4],
                                         float (&out)[5]){
    float h = 0.0f, c = 0.0f;
    #pragma unroll
    for (int t = 0; t < 5; ++t){
        float q0 = acc[t][0], q1 = acc[t][1], q2 = acc[t][2], q3 = acc[t][3];
        if (t > 0){
            #pragma unroll
            for (int k = 0; k < 32; ++k){
                float hk = __shfl(h, k, 32);   // broadcast h_k within the 32-lane half-wave
                q0 = fmaf(wh[0][k], hk, q0);
                q1 = fmaf(wh[1][k], hk, q1);
                q2 = fmaf(wh[2][k], hk, q2);
                q3 = fmaf(wh[3][k], hk, q3);
            }
        }
        float iv = fsig(q0), fv = fsig(q1), gv = ftanh(q2), ov = fsig(q3);
        c = fmaf(fv, c, iv * gv);
        h = ov * ftanh(c);
        out[t] = h;
    }
}

// LayerNorm over (T,H)=160 jointly + LeakyReLU, in place; g/b read direct (coalesced, L2-hot)
__device__ __forceinline__ void ln_lrelu(float (&o)[5], const float* __restrict__ gs,
                                         const float* __restrict__ bs, int j){
    float s1 = 0.0f, s2 = 0.0f;
    #pragma unroll
    for (int t = 0; t < 5; ++t){ s1 += o[t]; s2 = fmaf(o[t], o[t], s2); }
    #pragma unroll
    for (int m = 1; m < 32; m <<= 1){
        s1 += __shfl_xor(s1, m, 64);   // masks <32 stay within the half-wave
        s2 += __shfl_xor(s2, m, 64);
    }
    float mu   = s1 * (1.0f/160.0f);
    float var  = s2 * (1.0f/160.0f) - mu*mu;
    float rstd = rsqrtf(var + 1e-5f);
    #pragma unroll
    for (int t = 0; t < 5; ++t){
        float y = (o[t] - mu) * rstd;
        y = fmaf(y, gs[t*32 + j], bs[t*32 + j]);
        o[t] = lrelu(y);
    }
}

// Occupancy arc closed (R0-R8): per-lane semantic floor ~100-116 VGPR -> 2 waves/SIMD
// is structural ((256,3)=85 spilled 9.4GB in R8; (256,4)=64 spilled in R1).
// THIS round's lever: PHASE DIVERSITY. 1-wave blocks -> the 2 waves co-resident on a
// SIMD are independent blocks at independent phases; one wave's serial-recurrence
// stalls are filled by the other's phase-A FMAs. No shared staging -> no lockstep.
// (64,2) = 128-reg budget >= ~116 floor: feasible clamp, blocks R7-style hoisting.
__global__ __launch_bounds__(THREADS, 2)
void reslstm_kernel(const float* __restrict__ data,
                    const float* __restrict__ wih0, const float* __restrict__ whh0,
                    const float* __restrict__ bih0, const float* __restrict__ bhh0,
                    const float* __restrict__ g0p,  const float* __restrict__ be0p,
                    const float* __restrict__ wih1, const float* __restrict__ whh1,
                    const float* __restrict__ bih1, const float* __restrict__ bhh1,
                    const float* __restrict__ g1p,  const float* __restrict__ be1p,
                    const float* __restrict__ dwp,  const float* __restrict__ dbp,
                    float* __restrict__ outp, int Btot)
{
    // ~4.2 KB LDS: occupancy never LDS-limited; weights are NOT staged (L1/L2-hot
    // global reads, identical rows for every block -> cache-served).
    __shared__ __attribute__((aligned(16))) float xs[SPB*320];    // x [s][t][64], pad n=62,63
    __shared__ __attribute__((aligned(16))) float o0s[SPB*160];   // out0 lines for phase-B reads

    const int tid = threadIdx.x;
    const int b0  = blockIdx.x * SPB;
    const int nsamp = (Btot - b0 < SPB) ? (Btot - b0) : SPB;

    // ---------------- stage x only (coalesced fp32 global -> LDS) ----------------
    {
        const float* dat = data + (size_t)b0 * 310;   // sample chunk: idx = n*5 + t
        for (int i = tid; i < nsamp*310; i += THREADS){
            int s = i / 310, r = i - s*310;
            int n = r / 5,   t = r - n*5;
            xs[s*320 + t*64 + n] = dat[i];
        }
        if (tid < SPB*10){                             // zero pad n=62,63
            int s = tid / 10, q = tid - s*10;
            xs[s*320 + (q>>1)*64 + 62 + (q&1)] = 0.0f;
        }
    }
    __syncthreads();   // 1-wave barrier: compiles to a waitcnt, essentially free

    const int j = tid & 31;       // hidden unit owned by this lane
    const int s = tid >> 5;       // sample-in-block (half-wave)
    const float* xp = xs  + s*320;
    float*       ol = o0s + s*160;

    // ---------------- phase A: xg0 = x @ W_ih0^T + biases ----------------
    // w rows from GLOBAL (row stride 62 floats = 248 B -> 8B-aligned: float2 loads).
    // Both half-waves read the SAME rows -> 32 distinct addresses/request, L1-hot.
    float acc[5][4];
    #pragma unroll
    for (int r = 0; r < 4; ++r)
    {
        float bv = bih0[r*32 + j] + bhh0[r*32 + j];
        #pragma unroll
        for (int t = 0; t < 5; ++t) acc[t][r] = bv;
    }
    {
        const float* w0 = wih0 + (size_t)(0*32 + j)*62;
        const float* w1 = wih0 + (size_t)(1*32 + j)*62;
        const float* w2 = wih0 + (size_t)(2*32 + j)*62;
        const float* w3 = wih0 + (size_t)(3*32 + j)*62;
        #pragma unroll 5
        for (int n0 = 0; n0 < 60; n0 += 4){
            float2 a0 = *(const float2*)(w0 + n0), b0v = *(const float2*)(w0 + n0 + 2);
            float2 a1 = *(const float2*)(w1 + n0), b1v = *(const float2*)(w1 + n0 + 2);
            float2 a2 = *(const float2*)(w2 + n0), b2v = *(const float2*)(w2 + n0 + 2);
            float2 a3 = *(const float2*)(w3 + n0), b3v = *(const float2*)(w3 + n0 + 2);
            #pragma unroll
            for (int t = 0; t < 5; ++t){
                float4 xv = *(const float4*)(xp + t*64 + n0);   // half-wave broadcast
                acc[t][0] = fmaf(a0.x,xv.x, fmaf(a0.y,xv.y, fmaf(b0v.x,xv.z, fmaf(b0v.y,xv.w, acc[t][0]))));
                acc[t][1] = fmaf(a1.x,xv.x, fmaf(a1.y,xv.y, fmaf(b1v.x,xv.z, fmaf(b1v.y,xv.w, acc[t][1]))));
                acc[t][2] = fmaf(a2.x,xv.x, fmaf(a2.y,xv.y, fmaf(b2v.x,xv.z, fmaf(b2v.y,xv.w, acc[t][2]))));
                acc[t][3] = fmaf(a3.x,xv.x, fmaf(a3.y,xv.y, fmaf(b3v.x,xv.z, fmaf(b3v.y,xv.w, acc[t][3]))));
            }
        }
        // tail n = 60,61
        float2 t0 = *(const float2*)(w0 + 60);
        float2 t1 = *(const float2*)(w1 + 60);
        float2 t2 = *(const float2*)(w2 + 60);
        float2 t3 = *(const float2*)(w3 + 60);
        #pragma unroll
        for (int t = 0; t < 5; ++t){
            float2 xv = *(const float2*)(xp + t*64 + 60);
            acc[t][0] = fmaf(t0.x,xv.x, fmaf(t0.y,xv.y, acc[t][0]));
            acc[t][1] = fmaf(t1.x,xv.x, fmaf(t1.y,xv.y, acc[t][1]));
            acc[t][2] = fmaf(t2.x,xv.x, fmaf(t2.y,xv.y, acc[t][2]));
            acc[t][3] = fmaf(t3.x,xv.x, fmaf(t3.y,xv.y, acc[t][3]));
        }
    }

    // ---------------- layer 0 recurrence + LN + LeakyReLU ----------------
    float o0[5];
    {
        float wh[4][32];
        load_wh_global(whh0, j, wh);
        lstm_rec(wh, acc, o0);
    }
    ln_lrelu(o0, g0p, be0p, j);
    #pragma unroll
    for (int t = 0; t < 5; ++t) ol[t*32 + j] = o0[t];
    __syncthreads();   // 1-wave barrier (orders o0s write -> cross-lane float4 reads)

    // ---------------- phase B: xg1 = out0 @ W_ih1^T + biases ----------------
    // wih1 rows stride 32 floats = 128 B -> 16B-aligned: float4 loads, L1-hot.
    #pragma unroll
    for (int r = 0; r < 4; ++r){
        float bv = bih1[r*32 + j] + bhh1[r*32 + j];
        #pragma unroll
        for (int t = 0; t < 5; ++t) acc[t][r] = bv;
    }
    {
        const float* w0 = wih1 + (size_t)(0*32 + j)*32;
        const float* w1 = wih1 + (size_t)(1*32 + j)*32;
        const float* w2 = wih1 + (size_t)(2*32 + j)*32;
        const float* w3 = wih1 + (size_t)(3*32 + j)*32;
        #pragma unroll 2
        for (int k0 = 0; k0 < 32; k0 += 4){
            float4 u0 = *(const float4*)(w0 + k0);
            float4 u1 = *(const float4*)(w1 + k0);
            float4 u2 = *(const float4*)(w2 + k0);
            float4 u3 = *(const float4*)(w3 + k0);
            #pragma unroll
            for (int t = 0; t < 5; ++t){
                float4 ov = *(const float4*)(ol + t*32 + k0);
                acc[t][0] = fmaf(u0.x,ov.x, fmaf(u0.y,ov.y, fmaf(u0.z,ov.z, fmaf(u0.w,ov.w, acc[t][0]))));
                acc[t][1] = fmaf(u1.x,ov.x, fmaf(u1.y,ov.y, fmaf(u1.z,ov.z, fmaf(u1.w,ov.w, acc[t][1]))));
                acc[t][2] = fmaf(u2.x,ov.x, fmaf(u2.y,ov.y, fmaf(u2.z,ov.z, fmaf(u2.w,ov.w, acc[t][2]))));
                acc[t][3] = fmaf(u3.x,ov.x, fmaf(u3.y,ov.y, fmaf(u3.z,ov.z, fmaf(u3.w,ov.w, acc[t][3]))));
            }
        }
    }

    // ---------------- layer 1 recurrence + LN + residual ----------------
    float o1[5];
    {
        float wh[4][32];
        load_wh_global(whh1, j, wh);
        lstm_rec(wh, acc, o1);
    }
    ln_lrelu(o1, g1p, be1p, j);
    #pragma unroll
    for (int t = 0; t < 5; ++t) o1[t] += o0[t];   // residual

    // ---------------- dense head: (160) @ dw^T + db, LeakyReLU (dw direct, coalesced) ----------------
    float p0 = 0.0f, p1 = 0.0f, p2 = 0.0f;
    #pragma unroll
    for (int t = 0; t < 5; ++t){
        float v = o1[t];
        int ix = t*32 + j;
        p0 = fmaf(dwp[      ix], v, p0);
        p1 = fmaf(dwp[160 + ix], v, p1);
        p2 = fmaf(dwp[320 + ix], v, p2);
    }
    #pragma unroll
    for (int m = 1; m < 32; m <<= 1){
        p0 += __shfl_xor(p0, m, 64);
        p1 += __shfl_xor(p1, m, 64);
        p2 += __shfl_xor(p2, m, 64);
    }
    if (j < 3 && s < nsamp){
        float v = (j == 0) ? p0 : ((j == 1) ? p1 : p2);
        v = lrelu(v + dbp[j]);
        outp[(size_t)(b0 + s)*3 + j] = v;
    }
}

extern "C" void kernel_launch(void* const* d_in, const int* in_sizes, int n_in,
                              void* d_out, int out_size, void* d_ws, size_t ws_size,
                              hipStream_t stream)
{
    (void)d_ws; (void)ws_size;

    const int B = out_size / 3;

    // Locate 'data' = largest input; infer the harness's input ordering from it.
    int idx_data = 0;
    for (int i = 1; i < n_in; ++i)
        if (in_sizes[i] > in_sizes[idx_data]) idx_data = i;

    // semantic slots (reference dict order):
    // 0 data,1 wih0,2 whh0,3 bih0,4 bhh0,5 g0,6 be0,7 wih1,8 whh1,9 bih1,
    // 10 bhh1,11 g1,12 be1,13 dw,14 db
    static const int dict_map[15]  = {0,1,2,3,4,5,6,7,8,9,10,11,12,13,14};
    // alphabetical key order fallback
    static const int alpha_map[15] = {6,13,11,2,0,9,4,14,12,3,1,10,5,8,7};
    static const int rev_map[15]   = {14,13,12,11,10,9,8,7,6,5,4,3,2,1,0};

    const int* map = dict_map;
    if (idx_data == 6)       map = alpha_map;
    else if (idx_data == 14) map = rev_map;

    long ds  = (long)in_sizes[idx_data];
    long ws0 = (long)in_sizes[map[1]];
    bool ok = (ds == (long)B*310 || ds == (long)B*620 || ds == (long)B*1240)
           && (ws0 == 7936 || ws0 == 15872 || ws0 == 31744);

    if (!ok || B <= 0){
        diag_kernel<<<1, 1, 0, stream>>>((float*)d_out, 100.0f + 10.0f*idx_data);
        return;
    }

    const float* P[15];
    for (int k = 0; k < 15; ++k) P[k] = (const float*)d_in[map[k]];

    const int nblocks = (B + SPB - 1) / SPB;
    reslstm_kernel<<<dim3(nblocks), dim3(THREADS), 0, stream>>>(
        P[0], P[1], P[2], P[3], P[4], P[5], P[6], P[7], P[8], P[9],
        P[10], P[11], P[12], P[13], P[14],
        (float*)d_out, B);
}